// Round 4
// baseline (557.263 us; speedup 1.0000x reference)
//
#include <hip/hip_runtime.h>
#include <hip/hip_fp16.h>

// ---- problem constants (fixed by setup_inputs) ----
constexpr int B_ = 8, T_ = 2048, M_ = 1024, F_ = 2048, E_ = 8;
constexpr int S_   = B_ * T_;     // 16384 tokens
constexpr int CAP  = 2048;        // capacity = ceil(S/E)
constexpr int DUMP = E_ * CAP;    // 16384 (dropped-token sentinel)
#define HASHP 5099

typedef _Float16 h4_t  __attribute__((ext_vector_type(4)));
typedef _Float16 h8_t  __attribute__((ext_vector_type(8)));
typedef float    f32x4 __attribute__((ext_vector_type(4)));

// ---- async global->LDS (width 16B). LDS dest is wave-uniform base + lane*16.
__device__ __forceinline__ void gload_lds16(const _Float16* g, _Float16* l) {
  __builtin_amdgcn_global_load_lds(
      (const __attribute__((address_space(1))) void*)g,
      (__attribute__((address_space(3))) void*)l, 16, 0, 0);
}

// ============================================================
// 1) routing: flat_idx[s] = e*CAP + rank  (or DUMP if dropped)
// ============================================================
__global__ __launch_bounds__(256) void route_kernel(const int* __restrict__ tok,
                                                    int* __restrict__ flat_idx) {
  __shared__ unsigned char se[S_];     // 16 KB: expert id per token
  __shared__ int cnt[256][8];          // 8 KB : per-thread-chunk counts -> prefix
  const int t = threadIdx.x;
#pragma unroll
  for (int i = 0; i < S_ / 256; ++i) { // coalesced token load
    const int s = i * 256 + t;
    se[s] = (unsigned char)((tok[s] * HASHP) & (E_ - 1));
  }
  __syncthreads();
#pragma unroll
  for (int e = 0; e < 8; ++e) cnt[t][e] = 0;
  const int base = t * 64;             // each thread owns 64 consecutive tokens
  for (int i = 0; i < 64; ++i) cnt[t][se[base + i]]++;
  __syncthreads();
  if (t < 8) {                         // exclusive scan across the 256 chunks
    int run = 0;
    for (int i = 0; i < 256; ++i) { const int tmp = cnt[i][t]; cnt[i][t] = run; run += tmp; }
  }
  __syncthreads();
  for (int i = 0; i < 64; ++i) {
    const int e = se[base + i];
    const int p = cnt[t][e]++;
    flat_idx[base + i] = (p < CAP) ? e * CAP + p : DUMP;
  }
}

// ============================================================
// 2) weight transpose + f32->f16:  in (E,R,C) f32 -> out (E,C,R) f16
// ============================================================
__global__ __launch_bounds__(256) void transpose_cvt(const float* __restrict__ in,
                                                     _Float16* __restrict__ out,
                                                     int R, int C) {
  __shared__ float tile[32][33];       // +1 pad: conflict-free column read
  const int e  = blockIdx.z;
  const int c0 = blockIdx.x * 32, r0 = blockIdx.y * 32;
  const int tx = threadIdx.x, ty = threadIdx.y;    // (32, 8)
  const size_t ib = (size_t)e * R * C;
#pragma unroll
  for (int i = 0; i < 4; ++i)
    tile[ty + i * 8][tx] = in[ib + (size_t)(r0 + ty + i * 8) * C + c0 + tx];
  __syncthreads();
#pragma unroll
  for (int i = 0; i < 4; ++i)
    out[ib + (size_t)(c0 + ty + i * 8) * R + r0 + tx] = (_Float16)tile[tx][ty + i * 8];
}

// ============================================================
// 3) token-shift mix + dispatch scatter. MODE 0: write dr only.
//    MODE 1: write dk + new_shift_state.
// ============================================================
template <int MODE>
__global__ __launch_bounds__(256) void scatter_kernel(
    const float* __restrict__ x, const float* __restrict__ shift,
    const float* __restrict__ tm,          // time_maa_r (MODE 0) or time_maa_k (MODE 1)
    const int* __restrict__ flat_idx,
    _Float16* __restrict__ d,              // dr (MODE 0) or dk (MODE 1)
    float* __restrict__ out_shift) {
  const int s = blockIdx.x;
  const int b = s >> 11, t = s & (T_ - 1);
  const int j = threadIdx.x * 4;
  const float4 xv = *(const float4*)(x + (size_t)s * M_ + j);
  const int slot = flat_idx[s];
  if (slot != DUMP) {
    float4 xp;
    if (t == 0) xp = *(const float4*)(shift + (size_t)b * M_ + j);
    else        xp = *(const float4*)(x + (size_t)(s - 1) * M_ + j);
    const float4 tv = *(const float4*)(tm + j);
    h4_t o;
    o[0] = (_Float16)(xv.x + (xp.x - xv.x) * tv.x);
    o[1] = (_Float16)(xv.y + (xp.y - xv.y) * tv.y);
    o[2] = (_Float16)(xv.z + (xp.z - xv.z) * tv.z);
    o[3] = (_Float16)(xv.w + (xp.w - xv.w) * tv.w);
    *(h4_t*)(d + (size_t)slot * M_ + j) = o;
  }
  if (MODE == 1 && t == T_ - 1) *(float4*)(out_shift + (size_t)b * M_ + j) = xv;
}

// ============================================================
// 4) grouped GEMM, m97 structure: 128x128 tile, BK=64, 4 waves,
//    A (M,K) row-major f16, Bt (N,K) row-major f16, C (M,N) f16.
//    EPI: 0 = none, 1 = relu^2, 2 = sigmoid
// ============================================================
template <int EPI>
__global__ __launch_bounds__(256, 2)
void gemm_kernel(const _Float16* __restrict__ A, const _Float16* __restrict__ Bt,
                 _Float16* __restrict__ C, int M, int N, int K) {
  const int e = blockIdx.z;
  const _Float16* Ab = A  + (size_t)e * M * K + (size_t)blockIdx.y * 128 * K;
  const _Float16* Bb = Bt + (size_t)e * N * K + (size_t)blockIdx.x * 128 * K;
  _Float16*       Cb = C  + (size_t)e * M * N + (size_t)blockIdx.y * 128 * N + blockIdx.x * 128;

  __shared__ __align__(16) _Float16 sA[128 * 64];
  __shared__ __align__(16) _Float16 sB[128 * 64];

  const int tid  = threadIdx.x;
  const int lane = tid & 63;
  const int w    = tid >> 6;          // wave 0..3 in 2x2 grid
  const int wr   = (w >> 1) * 64;
  const int wc   = (w & 1) * 64;
  const int srow = lane >> 3;         // staging coords
  const int scol = (lane & 7) * 8;
  const int fr   = lane & 15;         // fragment row/col
  const int fk   = (lane >> 4) * 8;   // fragment k-offset

  f32x4 acc[4][4] = {};

  for (int kt = 0; kt < K; kt += 64) {
#pragma unroll
    for (int i = 0; i < 4; ++i) {                 // 16 chunks of 1KB each
      const int chunk = w * 4 + i;                // wave-uniform
      const int row   = chunk * 8 + srow;
      gload_lds16(Ab + (size_t)row * K + kt + scol, sA + chunk * 512);
      gload_lds16(Bb + (size_t)row * K + kt + scol, sB + chunk * 512);
    }
    __syncthreads();                              // drains vmcnt -> tile ready
#pragma unroll
    for (int kk = 0; kk < 2; ++kk) {
      h8_t a[4], b[4];
#pragma unroll
      for (int i = 0; i < 4; ++i) {
        a[i] = *(const h8_t*)&sA[(wr + i * 16 + fr) * 64 + kk * 32 + fk];
        b[i] = *(const h8_t*)&sB[(wc + i * 16 + fr) * 64 + kk * 32 + fk];
      }
#pragma unroll
      for (int mi = 0; mi < 4; ++mi)
#pragma unroll
        for (int ni = 0; ni < 4; ++ni)
          acc[mi][ni] = __builtin_amdgcn_mfma_f32_16x16x32_f16(a[mi], b[ni], acc[mi][ni], 0, 0, 0);
    }
    __syncthreads();
  }

  // epilogue: C/D layout col = lane&15, row = (lane>>4)*4 + j  [m89/m91]
#pragma unroll
  for (int mi = 0; mi < 4; ++mi)
#pragma unroll
    for (int ni = 0; ni < 4; ++ni)
#pragma unroll
      for (int j = 0; j < 4; ++j) {
        const int row = wr + mi * 16 + (lane >> 4) * 4 + j;
        const int col = wc + ni * 16 + fr;
        float v = acc[mi][ni][j];
        if (EPI == 1) { v = fmaxf(v, 0.f); v = v * v; }
        if (EPI == 2) { v = 1.f / (1.f + __expf(-v)); }
        Cb[(size_t)row * N + col] = (_Float16)v;
      }
}

// ============================================================
// 5) combine gather: out = r * kv  (zeros for dropped tokens)
// ============================================================
__global__ __launch_bounds__(256) void gather_kernel(
    const _Float16* __restrict__ r, const _Float16* __restrict__ kv,
    const int* __restrict__ flat_idx, float* __restrict__ out) {
  const int s = blockIdx.x;
  const int j = threadIdx.x * 4;
  const int slot = flat_idx[s];
  float4 o;
  if (slot != DUMP) {
    const h4_t rv  = *(const h4_t*)(r  + (size_t)slot * M_ + j);
    const h4_t kvv = *(const h4_t*)(kv + (size_t)slot * M_ + j);
    o.x = (float)rv[0] * (float)kvv[0];
    o.y = (float)rv[1] * (float)kvv[1];
    o.z = (float)rv[2] * (float)kvv[2];
    o.w = (float)rv[3] * (float)kvv[3];
  } else {
    o.x = o.y = o.z = o.w = 0.f;
  }
  *(float4*)(out + (size_t)s * M_ + j) = o;
}

// ============================================================
// Workspace plan (96.07 MiB peak — was 272 MiB, which overflowed d_ws):
//   flat_idx : 64 KB
//   bufA 32M : dr  -> dk  -> kv      (each lifetime disjoint)
//   bufB 32M : r
//   WT   32M : WrT -> WkT -> WvT     (consumed before next transpose)
//   h (64 MiB) lives in d_out's `out` region (only gather writes `out`,
//   and gather reads nothing from it; out_shift sits past the h span).
// ============================================================
extern "C" void kernel_launch(void* const* d_in, const int* in_sizes, int n_in,
                              void* d_out, int out_size, void* d_ws, size_t ws_size,
                              hipStream_t stream) {
  const float* x     = (const float*)d_in[0];
  const int*   tok   = (const int*)  d_in[1];
  const float* shift = (const float*)d_in[2];
  const float* tmk   = (const float*)d_in[3];
  const float* tmr   = (const float*)d_in[4];
  const float* Wk    = (const float*)d_in[5];
  const float* Wv    = (const float*)d_in[6];
  const float* Wr    = (const float*)d_in[7];
  float* out       = (float*)d_out;                 // (B,T,m) f32
  float* out_shift = out + (size_t)S_ * M_;         // (B,m)   f32
  _Float16* h      = (_Float16*)d_out;              // scratch: exactly 64 MiB

  char* ws = (char*)d_ws;
  size_t off = 0;
  auto alloc = [&](size_t bytes) { char* p = ws + off; off += (bytes + 255) & ~(size_t)255; return p; };
  int*      flat_idx = (int*)     alloc((size_t)S_ * 4);
  _Float16* bufA = (_Float16*)alloc((size_t)S_ * M_ * 2);        // 32 MiB
  _Float16* bufB = (_Float16*)alloc((size_t)S_ * M_ * 2);        // 32 MiB
  _Float16* WT   = (_Float16*)alloc((size_t)E_ * M_ * F_ * 2);   // 32 MiB

  route_kernel<<<1, 256, 0, stream>>>(tok, flat_idx);

  // ---- r branch first (so dr's buffer can be recycled for dk/kv) ----
  transpose_cvt<<<dim3(M_ / 32, M_ / 32, E_), dim3(32, 8), 0, stream>>>(Wr, WT, M_, M_);
  scatter_kernel<0><<<S_, 256, 0, stream>>>(x, shift, tmr, flat_idx, bufA, nullptr);
  // r = sigmoid(dr @ Wr)   M=CAP N=1024 K=1024
  gemm_kernel<2><<<dim3(M_ / 128, CAP / 128, E_), 256, 0, stream>>>(bufA, WT, bufB, CAP, M_, M_);

  // ---- k branch ----
  transpose_cvt<<<dim3(F_ / 32, M_ / 32, E_), dim3(32, 8), 0, stream>>>(Wk, WT, M_, F_);
  scatter_kernel<1><<<S_, 256, 0, stream>>>(x, shift, tmk, flat_idx, bufA, out_shift);
  // h = relu(dk @ Wk)^2    M=CAP N=2048 K=1024   (h -> d_out scratch)
  gemm_kernel<1><<<dim3(F_ / 128, CAP / 128, E_), 256, 0, stream>>>(bufA, WT, h, CAP, F_, M_);

  transpose_cvt<<<dim3(M_ / 32, F_ / 32, E_), dim3(32, 8), 0, stream>>>(Wv, WT, F_, M_);
  // kv = h @ Wv            M=CAP N=1024 K=2048   (kv -> bufA, dk dead)
  gemm_kernel<0><<<dim3(M_ / 128, CAP / 128, E_), 256, 0, stream>>>(h, WT, bufA, CAP, M_, F_);

  // ---- combine: out = r * kv (overwrites h region; reads only r/kv/idx) ----
  gather_kernel<<<S_, 256, 0, stream>>>(bufB, bufA, flat_idx, out);
}